// Round 1
// baseline (120.448 us; speedup 1.0000x reference)
//
#include <hip/hip_runtime.h>
#include <hip/hip_bf16.h>
#include <math.h>

#define INPUT_DIM 256
#define OUT_DIM   256
#define NDEG      8                    // degree+1
#define KTOT      (INPUT_DIM * NDEG)   // 2048
#define NROWS     (16 * 2048)          // 32768

#define BM  128                        // block rows (featurize exactly once globally)
#define BK  64                         // 8 inputs * 8 degrees per K-chunk
#define NK  (KTOT / BK)                // 32
#define CHUNK_ELEMS 16384              // full-width B chunk: 256 o * 64 k

typedef __bf16 bf16x8 __attribute__((ext_vector_type(8)));
typedef float  f32x16 __attribute__((ext_vector_type(16)));

// ---------------------------------------------------------------------------
// Kernel 1: reorder coeffs C[i][o][d] (fp32) -> B pages (bf16). Unchanged R9
// layout: page = one wave-frag load (1 KB), frag(kc,s,c,ni) at
//   kc*16384 + (s*4+c)*1024 + ni*512 + h*256 + l31*8 + d
// ---------------------------------------------------------------------------
__global__ __launch_bounds__(256) void reorder_coeffs(const float* __restrict__ C,
                                                      __bf16* __restrict__ Bt) {
    int g = blockIdx.x * 256 + threadIdx.x;   // 65536 = 256 i * 256 o
    int i = g >> 8;
    int o = g & 255;
    const float4* src = (const float4*)(C + (size_t)i * (OUT_DIM * NDEG) + o * NDEG);
    float4 a = src[0];
    float4 b = src[1];
    bf16x8 v;
    v[0] = (__bf16)a.x; v[1] = (__bf16)a.y; v[2] = (__bf16)a.z; v[3] = (__bf16)a.w;
    v[4] = (__bf16)b.x; v[5] = (__bf16)b.y; v[6] = (__bf16)b.z; v[7] = (__bf16)b.w;
    int kc = i >> 3;
    int p  = i & 7;
    int s  = p >> 1;
    int hh = p & 1;
    int cc = o >> 6;
    int ni = (o >> 5) & 1;
    int l31 = o & 31;
    size_t dst = (size_t)kc * CHUNK_ELEMS + (s * 4 + cc) * 1024 + ni * 512 + hh * 256 + l31 * 8;
    *(bf16x8*)(Bt + dst) = v;   // 16B-aligned
}

// tanh + physicists' Hermite recurrence -> 8 degrees as bf16x8
__device__ __forceinline__ bf16x8 featurize(float xs) {
    float e = __expf(2.0f * xs);            // tanh(x)=1-2/(e^{2x}+1), robust all x
    float t = 1.0f - 2.0f / (e + 1.0f);
    bf16x8 v;
    float hm2 = 1.0f;                       // H_0
    float hm1 = 2.0f * t;                   // H_1
    v[0] = (__bf16)hm2;
    v[1] = (__bf16)hm1;
    #pragma unroll
    for (int d = 2; d < 8; ++d) {
        float h = 2.0f * t * hm1 - 2.0f * (float)(d - 1) * hm2;
        v[d] = (__bf16)h;
        hm2 = hm1; hm1 = h;
    }
    return v;
}

// lgkm-only barrier (R10): do NOT drain vmcnt. Each wave's own LDS writes and
// reads are complete (lgkmcnt(0)) before it signals arrival, which is the full
// producer/consumer requirement for the Alds double buffer. B/x prefetch loads
// target registers (per-wave private) and carry the compiler's vmcnt waits at
// their use sites -- they legally stay in flight across the barrier. The asm
// memory clobbers pin LDS op ordering on both sides (volatile ops keep mutual
// order, LDS ops cannot cross a "memory" clobber).
#define BARRIER() do {                                             \
    asm volatile("s_waitcnt lgkmcnt(0)" ::: "memory");             \
    __builtin_amdgcn_s_barrier();                                  \
    asm volatile("" ::: "memory");                                 \
} while (0)

// ---------------------------------------------------------------------------
// Kernel 2 (Round 10): R9 architecture widened to BM=128 / 8 waves / grid 256
// (1 block/CU, m201-style), plus lgkm-only barriers.
//  Why: R9 counters showed MfmaUtil 27% with 0 bank conflicts and 13% HBM --
//  latency/L2-bound. Per-CU/STEP: MFMA 1024 cyc vs B-from-L2 64 KB ~ 1170 cyc
//  (co-critical) + vmcnt(0) drain at every __syncthreads pinning x HBM latency.
//  - BM=128 halves B L2 traffic (512->256 MB); wave pairs (mr=0/1, same c)
//    read identical 1 KB pages -> L1 turns duplication into hits.
//  - Wave tile stays 64x64 (16 MFMA : 8 ds_read_b128 keeps LDS at ~75% of
//    MFMA shadow; 64x32 tiles would be LDS-bound).
//  - One lgkm-only barrier per STEP; B/x prefetches span barriers.
// Block 512 thr / 8 waves (2 mr x 4 c), tile 128x256, wave tile 64x64.
// ---------------------------------------------------------------------------
__global__ __launch_bounds__(512, 2) void hermite_mfma(const float* __restrict__ x,
                                                       const __bf16* __restrict__ Bt,
                                                       float* __restrict__ out) {
    __shared__ __align__(16) __bf16 Alds[2][8192];   // [buf][p*1024 + m*8], 32 KB

    const int tid  = threadIdx.x;
    const int bm   = blockIdx.x;       // 0..255
    const int wave = tid >> 6;         // 0..7
    const int mr   = wave >> 2;        // 0..1 : row half (rows mr*64..mr*64+63)
    const int c    = wave & 3;         // 0..3 : column slice (cols c*64..c*64+63)
    const int lane = tid & 63;
    const int l31  = lane & 31;
    const int h    = lane >> 5;

    // Featurize mapping: thread -> (row m, input pair pg*2+{0,1}); 1x global.
    const int m  = tid & 127;
    const int pg = tid >> 7;           // 0..3
    const float* xptr = x + (size_t)(bm * BM + m) * INPUT_DIM + pg * 2;

    // B pages for this wave's column slice c: frag(kc,s,ni) at
    //   Bt + kc*16384 + (s*4+c)*1024 + ni*512 + lane*8
    const __bf16* bbase = Bt + (size_t)c * 1024 + lane * 8;

    f32x16 acc[2][2] = {};
    bf16x8 bfr0[4][2];                 // chunk buffer A (static names: no scratch)
    bf16x8 bfr1[4][2];                 // chunk buffer B

    // ---- prologue: chunk 0 ----
    float2 xv = *(const float2*)(xptr);
    #pragma unroll
    for (int s = 0; s < 4; ++s)
        #pragma unroll
        for (int ni = 0; ni < 2; ++ni)
            bfr0[s][ni] = *(const bf16x8*)(bbase + s * 4096 + ni * 512);
    *(bf16x8*)(&Alds[0][(pg * 2 + 0) * 1024 + m * 8]) = featurize(xv.x);
    *(bf16x8*)(&Alds[0][(pg * 2 + 1) * 1024 + m * 8]) = featurize(xv.y);
    xv = *(const float2*)(xptr + 8);   // chunk 1 x
    BARRIER();

    // One pipeline step; CUR/NXT and CB/NB are compile-time per expansion.
#define STEP(KC, CUR, NXT, CB, NB)                                           \
    {                                                                        \
        if ((KC) + 1 < NK) {                                                 \
            const __bf16* g = bbase + (size_t)((KC) + 1) * CHUNK_ELEMS;      \
            _Pragma("unroll")                                                \
            for (int s = 0; s < 4; ++s) {                                    \
                NXT[s][0] = *(const bf16x8*)(g + s * 4096);                  \
                NXT[s][1] = *(const bf16x8*)(g + s * 4096 + 512);            \
            }                                                                \
            *(bf16x8*)(&Alds[NB][(pg * 2 + 0) * 1024 + m * 8]) = featurize(xv.x); \
            *(bf16x8*)(&Alds[NB][(pg * 2 + 1) * 1024 + m * 8]) = featurize(xv.y); \
            int kn = ((KC) + 2 < NK) ? (KC) + 2 : NK - 1;                    \
            xv = *(const float2*)(xptr + kn * 8);                            \
        }                                                                    \
        _Pragma("unroll")                                                    \
        for (int s = 0; s < 4; ++s) {                                        \
            bf16x8 af0 = *(const bf16x8*)(&Alds[CB][(2 * s + h) * 1024 + mr * 512 + l31 * 8]);       \
            bf16x8 af1 = *(const bf16x8*)(&Alds[CB][(2 * s + h) * 1024 + mr * 512 + 256 + l31 * 8]); \
            acc[0][0] = __builtin_amdgcn_mfma_f32_32x32x16_bf16(af0, CUR[s][0], acc[0][0], 0, 0, 0); \
            acc[0][1] = __builtin_amdgcn_mfma_f32_32x32x16_bf16(af0, CUR[s][1], acc[0][1], 0, 0, 0); \
            acc[1][0] = __builtin_amdgcn_mfma_f32_32x32x16_bf16(af1, CUR[s][0], acc[1][0], 0, 0, 0); \
            acc[1][1] = __builtin_amdgcn_mfma_f32_32x32x16_bf16(af1, CUR[s][1], acc[1][1], 0, 0, 0); \
        }                                                                    \
        BARRIER();                                                           \
    }

    for (int kc2 = 0; kc2 < NK; kc2 += 2) {
        STEP(kc2,     bfr0, bfr1, 0, 1);
        STEP(kc2 + 1, bfr1, bfr0, 1, 0);
    }
#undef STEP

    // ---- epilogue: 32x32 C/D col=lane&31, row=(reg&3)+8*(reg>>2)+4*h (R7-validated) ----
    #pragma unroll
    for (int mi = 0; mi < 2; ++mi)
        #pragma unroll
        for (int ni = 0; ni < 2; ++ni) {
            #pragma unroll
            for (int r = 0; r < 16; ++r) {
                int rl  = (r & 3) + 8 * (r >> 2) + 4 * h;
                int row = bm * BM + mr * 64 + mi * 32 + rl;
                out[(size_t)row * OUT_DIM + c * 64 + ni * 32 + l31] = acc[mi][ni][r];
            }
        }
}

// ---------------------------------------------------------------------------
extern "C" void kernel_launch(void* const* d_in, const int* in_sizes, int n_in,
                              void* d_out, int out_size, void* d_ws, size_t ws_size,
                              hipStream_t stream) {
    const float* x = (const float*)d_in[0];          // [16,2048,256] fp32
    const float* C = (const float*)d_in[1];          // [256,256,8]  fp32
    float* out = (float*)d_out;                      // [16,2048,256] fp32
    __bf16* Bt = (__bf16*)d_ws;                      // paged [32][16384] bf16, 1 MB

    reorder_coeffs<<<dim3((INPUT_DIM * OUT_DIM) / 256), dim3(256), 0, stream>>>(C, Bt);
    hermite_mfma<<<dim3(NROWS / BM), dim3(512), 0, stream>>>(x, Bt, out);
}

// Round 2
// 115.082 us; speedup vs baseline: 1.0466x; 1.0466x over previous
//
#include <hip/hip_runtime.h>
#include <hip/hip_bf16.h>
#include <math.h>

#define INPUT_DIM 256
#define OUT_DIM   256
#define NDEG      8                    // degree+1
#define KTOT      (INPUT_DIM * NDEG)   // 2048
#define NROWS     (16 * 2048)          // 32768

#define BM  128                        // block rows (featurize exactly once globally)
#define BK  64                         // 8 inputs * 8 degrees per K-chunk
#define NK  (KTOT / BK)                // 32
#define SUPER 4                        // chunks per super-step (barrier granularity)
#define NSUP  (NK / SUPER)             // 8
#define CHUNK_ELEMS 16384              // full-width B chunk: 256 o * 64 k

typedef __bf16 bf16x8 __attribute__((ext_vector_type(8)));
typedef float  f32x16 __attribute__((ext_vector_type(16)));

// ---------------------------------------------------------------------------
// Kernel 1: reorder coeffs C[i][o][d] (fp32) -> B pages (bf16). Unchanged R9
// layout: page = one wave-frag load (1 KB), frag(kc,s,c,ni) at
//   kc*16384 + (s*4+c)*1024 + ni*512 + h*256 + l31*8 + d
// ---------------------------------------------------------------------------
__global__ __launch_bounds__(256) void reorder_coeffs(const float* __restrict__ C,
                                                      __bf16* __restrict__ Bt) {
    int g = blockIdx.x * 256 + threadIdx.x;   // 65536 = 256 i * 256 o
    int i = g >> 8;
    int o = g & 255;
    const float4* src = (const float4*)(C + (size_t)i * (OUT_DIM * NDEG) + o * NDEG);
    float4 a = src[0];
    float4 b = src[1];
    bf16x8 v;
    v[0] = (__bf16)a.x; v[1] = (__bf16)a.y; v[2] = (__bf16)a.z; v[3] = (__bf16)a.w;
    v[4] = (__bf16)b.x; v[5] = (__bf16)b.y; v[6] = (__bf16)b.z; v[7] = (__bf16)b.w;
    int kc = i >> 3;
    int p  = i & 7;
    int s  = p >> 1;
    int hh = p & 1;
    int cc = o >> 6;
    int ni = (o >> 5) & 1;
    int l31 = o & 31;
    size_t dst = (size_t)kc * CHUNK_ELEMS + (s * 4 + cc) * 1024 + ni * 512 + hh * 256 + l31 * 8;
    *(bf16x8*)(Bt + dst) = v;   // 16B-aligned
}

// tanh + physicists' Hermite recurrence -> 8 degrees as bf16x8
__device__ __forceinline__ bf16x8 featurize(float xs) {
    float e = __expf(2.0f * xs);            // tanh(x)=1-2/(e^{2x}+1), robust all x
    float t = 1.0f - 2.0f / (e + 1.0f);
    bf16x8 v;
    float hm2 = 1.0f;                       // H_0
    float hm1 = 2.0f * t;                   // H_1
    v[0] = (__bf16)hm2;
    v[1] = (__bf16)hm1;
    #pragma unroll
    for (int d = 2; d < 8; ++d) {
        float h = 2.0f * t * hm1 - 2.0f * (float)(d - 1) * hm2;
        v[d] = (__bf16)h;
        hm2 = hm1; hm1 = h;
    }
    return v;
}

// lgkm-only barrier: each wave's own LDS writes/reads complete (lgkmcnt(0))
// before it signals -- full producer/consumer requirement for the Alds dbuf.
// B/x prefetch loads target registers and carry compiler vmcnt waits at use
// sites; they legally stay in flight across the barrier.
#define BARRIER() do {                                             \
    asm volatile("s_waitcnt lgkmcnt(0)" ::: "memory");             \
    __builtin_amdgcn_s_barrier();                                  \
    asm volatile("" ::: "memory");                                 \
} while (0)

// ---------------------------------------------------------------------------
// Kernel 2 (Round 11): super-step restructure.
//  R10 post-mortem: per-STEP barriers align all waves to the same phase, so
//  VALU featurize (~800 cyc), LDS (~850 cyc) and MFMA (~1030 cyc) ADD instead
//  of overlapping -> 3830 cyc/STEP. Fix: A-LDS buffer = 4 chunks (64 KB x2 =
//  128 KB), barrier once per SUPER (8 total). Featurize for super s+1 is
//  interleaved between the 4 chunk-computes of super s in ONE barrier-free
//  region; disjoint deps (x regs -> buf NB vs buf CB + B regs -> acc) let the
//  2 waves/SIMD and per-wave ILP run VALU/LDS in the MFMA pipe's shadow.
//  BM=128 kept: 1 block/CU, B-from-L2 = 1 MB/CU/kernel (~19k cyc < 33k MFMA).
// Block 512 thr / 8 waves (2 mr x 4 c), tile 128x256, wave tile 64x64.
// ---------------------------------------------------------------------------
__global__ __launch_bounds__(512, 2) void hermite_mfma(const float* __restrict__ x,
                                                       const __bf16* __restrict__ Bt,
                                                       float* __restrict__ out) {
    // [buf][chunk-in-super cc*8192 + page j*1024 + m*8]; page = input (cc,j)
    __shared__ __align__(16) __bf16 Alds[2][SUPER * 8192];   // 128 KB

    const int tid  = threadIdx.x;
    const int bm   = blockIdx.x;       // 0..255
    const int wave = tid >> 6;         // 0..7
    const int mr   = wave >> 2;        // 0..1 : row half
    const int c    = wave & 3;         // 0..3 : column slice
    const int lane = tid & 63;
    const int l31  = lane & 31;
    const int h    = lane >> 5;

    // Featurize mapping: thread (m, pg) covers row m, inputs sup*32 + pg*8 + j
    // (j=0..7) == chunk-in-super pg, inputs-in-chunk 0..7. Exactly-once global.
    const int m  = tid & 127;
    const int pg = tid >> 7;           // 0..3
    const float* xptr = x + (size_t)(bm * BM + m) * INPUT_DIM + pg * 8;

    // B pages for column slice c: frag(kc,s,ni) at Bt + kc*16384 + (s*4+c)*1024
    //   + ni*512 + lane*8
    const __bf16* bbase = Bt + (size_t)c * 1024 + lane * 8;

    f32x16 acc[2][2] = {};
    bf16x8 bfr0[4][2];                 // chunk B-frag buffer A (static names)
    bf16x8 bfr1[4][2];                 // chunk B-frag buffer B

#define BLOAD(DST, KC)                                                       \
    if ((KC) < NK) {                                                         \
        const __bf16* g = bbase + (size_t)(KC) * CHUNK_ELEMS;                \
        _Pragma("unroll")                                                    \
        for (int s = 0; s < 4; ++s) {                                        \
            DST[s][0] = *(const bf16x8*)(g + s * 4096);                      \
            DST[s][1] = *(const bf16x8*)(g + s * 4096 + 512);                \
        }                                                                    \
    }

#define FEATW(NB, J, XS)                                                     \
    *(bf16x8*)(&Alds[NB][pg * 8192 + (J) * 1024 + m * 8]) = featurize(XS)

#define CHUNK_COMPUTE(CB, CC, CUR)                                           \
    _Pragma("unroll")                                                        \
    for (int s4 = 0; s4 < 4; ++s4) {                                         \
        bf16x8 af0 = *(const bf16x8*)(&Alds[CB][(CC) * 8192 + (2 * s4 + h) * 1024 + mr * 512 + l31 * 8]);       \
        bf16x8 af1 = *(const bf16x8*)(&Alds[CB][(CC) * 8192 + (2 * s4 + h) * 1024 + mr * 512 + 256 + l31 * 8]); \
        acc[0][0] = __builtin_amdgcn_mfma_f32_32x32x16_bf16(af0, CUR[s4][0], acc[0][0], 0, 0, 0); \
        acc[0][1] = __builtin_amdgcn_mfma_f32_32x32x16_bf16(af0, CUR[s4][1], acc[0][1], 0, 0, 0); \
        acc[1][0] = __builtin_amdgcn_mfma_f32_32x32x16_bf16(af1, CUR[s4][0], acc[1][0], 0, 0, 0); \
        acc[1][1] = __builtin_amdgcn_mfma_f32_32x32x16_bf16(af1, CUR[s4][1], acc[1][1], 0, 0, 0); \
    }

    // ---- prologue: featurize super 0 into buf 0, B chunk 0, x for super 1 ----
    float4 xq0 = *(const float4*)(xptr);
    float4 xq1 = *(const float4*)(xptr + 4);
    BLOAD(bfr0, 0);
    float4 xa0 = *(const float4*)(xptr + 32);
    float4 xa1 = *(const float4*)(xptr + 36);
    float4 xb0 = xa0, xb1 = xa1;       // init to silence uninitialized use
    FEATW(0, 0, xq0.x); FEATW(0, 1, xq0.y); FEATW(0, 2, xq0.z); FEATW(0, 3, xq0.w);
    FEATW(0, 4, xq1.x); FEATW(0, 5, xq1.y); FEATW(0, 6, xq1.z); FEATW(0, 7, xq1.w);
    BARRIER();

    // One super-step: compute 4 chunks from Alds[CB] + B reg dbuf; featurize
    // super S+1 from XC into Alds[NB], interleaved between chunk computes;
    // prefetch x for super S+2 into XN. Single barrier at the end.
#define SUPER_STEP(S, CB, NB, XC0, XC1, XN0, XN1)                            \
    {                                                                        \
        const bool dofeat = (S) + 1 < NSUP;                                  \
        BLOAD(bfr1, (S) * 4 + 1);                                            \
        if (dofeat) { FEATW(NB, 0, XC0.x); FEATW(NB, 1, XC0.y); }            \
        CHUNK_COMPUTE(CB, 0, bfr0);                                          \
        BLOAD(bfr0, (S) * 4 + 2);                                            \
        if (dofeat) { FEATW(NB, 2, XC0.z); FEATW(NB, 3, XC0.w); }            \
        CHUNK_COMPUTE(CB, 1, bfr1);                                          \
        BLOAD(bfr1, (S) * 4 + 3);                                            \
        if (dofeat) { FEATW(NB, 4, XC1.x); FEATW(NB, 5, XC1.y); }            \
        CHUNK_COMPUTE(CB, 2, bfr0);                                          \
        BLOAD(bfr0, (S) * 4 + 4);                                            \
        if (dofeat) { FEATW(NB, 6, XC1.z); FEATW(NB, 7, XC1.w); }            \
        if ((S) + 2 < NSUP) {                                                \
            XN0 = *(const float4*)(xptr + ((S) + 2) * 32);                   \
            XN1 = *(const float4*)(xptr + ((S) + 2) * 32 + 4);               \
        }                                                                    \
        CHUNK_COMPUTE(CB, 3, bfr1);                                          \
        BARRIER();                                                           \
    }

    for (int sp = 0; sp < NSUP; sp += 2) {
        SUPER_STEP(sp,     0, 1, xa0, xa1, xb0, xb1);
        SUPER_STEP(sp + 1, 1, 0, xb0, xb1, xa0, xa1);
    }
#undef SUPER_STEP
#undef CHUNK_COMPUTE
#undef FEATW
#undef BLOAD

    // ---- epilogue: 32x32 C/D col=lane&31, row=(reg&3)+8*(reg>>2)+4*h (R7-validated) ----
    #pragma unroll
    for (int mi = 0; mi < 2; ++mi)
        #pragma unroll
        for (int ni = 0; ni < 2; ++ni) {
            #pragma unroll
            for (int r = 0; r < 16; ++r) {
                int rl  = (r & 3) + 8 * (r >> 2) + 4 * h;
                int row = bm * BM + mr * 64 + mi * 32 + rl;
                out[(size_t)row * OUT_DIM + c * 64 + ni * 32 + l31] = acc[mi][ni][r];
            }
        }
}

// ---------------------------------------------------------------------------
extern "C" void kernel_launch(void* const* d_in, const int* in_sizes, int n_in,
                              void* d_out, int out_size, void* d_ws, size_t ws_size,
                              hipStream_t stream) {
    const float* x = (const float*)d_in[0];          // [16,2048,256] fp32
    const float* C = (const float*)d_in[1];          // [256,256,8]  fp32
    float* out = (float*)d_out;                      // [16,2048,256] fp32
    __bf16* Bt = (__bf16*)d_ws;                      // paged [32][16384] bf16, 1 MB

    reorder_coeffs<<<dim3((INPUT_DIM * OUT_DIM) / 256), dim3(256), 0, stream>>>(C, Bt);
    hermite_mfma<<<dim3(NROWS / BM), dim3(512), 0, stream>>>(x, Bt, out);
}